// Round 1
// baseline (325.236 us; speedup 1.0000x reference)
//
#include <hip/hip_runtime.h>
#include <math.h>

// Problem constants (from reference): B=4, N=4096, C=2048, E=64, K=2
#define T_TOKENS 16384
#define C_DIM    2048
#define N_SEQ    4096
#define E_EXP    64
#define KC       64      // K-chunk (channels per LDS stage)
#define TM       64      // tokens per block
#define LSTR     68      // LDS row stride (floats): pad 64->68, keeps 16B align,
                         // makes compute reads conflict-free (4*row mod 32 distinct)

// ---------------------------------------------------------------------------
// Kernel 1: ctx[b][j] = dot(routing_context[b,:], ctx_w[j,:])   (4 x 2048 out)
// One wave per output element; coalesced float4 row reads; butterfly reduce.
// ---------------------------------------------------------------------------
__global__ __launch_bounds__(256) void ctx_kernel(
    const float* __restrict__ rc, const float* __restrict__ ctx_w,
    float* __restrict__ ctx_out)
{
    const int w    = threadIdx.x >> 6;
    const int lane = threadIdx.x & 63;
    const int o    = blockIdx.x * 4 + w;         // 0..8191
    const int b    = o >> 11;                    // 0..3
    const int j    = o & 2047;                   // 0..2047

    const float4* wr = (const float4*)(ctx_w + (size_t)j * C_DIM);
    const float4* rr = (const float4*)(rc + (size_t)b * C_DIM);
    float s = 0.f;
#pragma unroll
    for (int it = 0; it < 8; ++it) {
        float4 a = wr[it * 64 + lane];
        float4 c = rr[it * 64 + lane];
        s += a.x * c.x + a.y * c.y + a.z * c.z + a.w * c.w;
    }
#pragma unroll
    for (int off = 32; off; off >>= 1) s += __shfl_xor(s, off, 64);
    if (lane == 0) ctx_out[b * C_DIM + j] = s;
}

// ---------------------------------------------------------------------------
// Kernel 2: per block: 64 tokens x 64 experts.
//   logits = (x + ctx[b]) @ gate_w^T  (fp32, 4 sub-accumulators per output)
//   then per-token: full softmax (importance), top-2 (+tie-break low index),
//   softmax over top-2 vals, write idx/weights, accumulate importance/load.
// ---------------------------------------------------------------------------
__global__ __launch_bounds__(256) void router_kernel(
    const float* __restrict__ x, const float* __restrict__ gate_w,
    const float* __restrict__ ctx, float* __restrict__ out,
    float* __restrict__ imp, float* __restrict__ cnt)
{
    __shared__ float xs[TM][LSTR];     // token tile (x + ctx)
    __shared__ float gs[E_EXP][LSTR];  // gate tile
    __shared__ float ls[TM][LSTR];     // logits for epilogue

    const int tid = threadIdx.x;
    const int eg  = tid & 15;          // expert group: e = eg + 16j
    const int tg  = tid >> 4;          // token group:  t = tg + 16i
    const int t0  = blockIdx.x * TM;
    const int b   = t0 / N_SEQ;

    const int sr  = tid >> 4;          // staging row group (0..15)
    const int scg = tid & 15;          // staging col group (float4)

    const float* ctx_row = ctx + (size_t)b * C_DIM;

    float4 acc[4][4];
#pragma unroll
    for (int i = 0; i < 4; ++i)
#pragma unroll
        for (int j = 0; j < 4; ++j)
            acc[i][j] = make_float4(0.f, 0.f, 0.f, 0.f);

    float4 px[4], pg[4], pc;
    auto prefetch = [&](int kc) {
        const int c0 = kc * KC + scg * 4;
        pc = *(const float4*)(ctx_row + c0);
#pragma unroll
        for (int i = 0; i < 4; ++i) {
            px[i] = *(const float4*)(x + (size_t)(t0 + sr + 16 * i) * C_DIM + c0);
            pg[i] = *(const float4*)(gate_w + (size_t)(sr + 16 * i) * C_DIM + c0);
        }
    };

    prefetch(0);
    const int NCHUNK = C_DIM / KC;     // 32
    for (int kc = 0; kc < NCHUNK; ++kc) {
        __syncthreads();               // readers done + prefetch loads drained
#pragma unroll
        for (int i = 0; i < 4; ++i) {
            float4 v = px[i];
            v.x += pc.x; v.y += pc.y; v.z += pc.z; v.w += pc.w;
            *(float4*)&xs[sr + 16 * i][scg * 4] = v;
            *(float4*)&gs[sr + 16 * i][scg * 4] = pg[i];
        }
        __syncthreads();               // LDS tile ready
        if (kc + 1 < NCHUNK) prefetch(kc + 1);  // in flight during compute
#pragma unroll
        for (int cc = 0; cc < KC; cc += 4) {
            float4 xv[4], gv[4];
#pragma unroll
            for (int i = 0; i < 4; ++i) xv[i] = *(const float4*)&xs[tg + 16 * i][cc];
#pragma unroll
            for (int j = 0; j < 4; ++j) gv[j] = *(const float4*)&gs[eg + 16 * j][cc];
#pragma unroll
            for (int i = 0; i < 4; ++i)
#pragma unroll
                for (int j = 0; j < 4; ++j) {
                    acc[i][j].x = fmaf(xv[i].x, gv[j].x, acc[i][j].x);
                    acc[i][j].y = fmaf(xv[i].y, gv[j].y, acc[i][j].y);
                    acc[i][j].z = fmaf(xv[i].z, gv[j].z, acc[i][j].z);
                    acc[i][j].w = fmaf(xv[i].w, gv[j].w, acc[i][j].w);
                }
        }
    }

    __syncthreads();
    // dump logits to LDS (pairwise horizontal sum of sub-accumulators)
#pragma unroll
    for (int i = 0; i < 4; ++i)
#pragma unroll
        for (int j = 0; j < 4; ++j)
            ls[tg + 16 * i][eg + 16 * j] =
                (acc[i][j].x + acc[i][j].y) + (acc[i][j].z + acc[i][j].w);
    __syncthreads();

    // Epilogue: wave w handles local tokens [16w, 16w+16); lane = expert
    const int wv   = tid >> 6;
    const int lane = tid & 63;
    float imp_acc = 0.f, cnt_acc = 0.f;

    for (int tt = 0; tt < 16; ++tt) {
        const int tokL = wv * 16 + tt;
        const float v = ls[tokL][lane];

        // argmax (tie -> lower index)
        float v1 = v; int i1 = lane;
#pragma unroll
        for (int off = 32; off; off >>= 1) {
            float ov = __shfl_xor(v1, off, 64);
            int   oi = __shfl_xor(i1, off, 64);
            if (ov > v1 || (ov == v1 && oi < i1)) { v1 = ov; i1 = oi; }
        }
        // full softmax for importance
        const float p = expf(v - v1);
        float s = p;
#pragma unroll
        for (int off = 32; off; off >>= 1) s += __shfl_xor(s, off, 64);
        imp_acc += p / s;

        // second max (exclude i1; tie -> lower index)
        float v2 = (lane == i1) ? -INFINITY : v; int i2 = lane;
#pragma unroll
        for (int off = 32; off; off >>= 1) {
            float ov = __shfl_xor(v2, off, 64);
            int   oi = __shfl_xor(i2, off, 64);
            if (ov > v2 || (ov == v2 && oi < i2)) { v2 = ov; i2 = oi; }
        }

        if (lane == i1 || lane == i2) cnt_acc += 1.f;  // i1,i2 wave-uniform

        if (lane == 0) {
            const int t = t0 + tokL;
            const float e2 = expf(v2 - v1);
            const float w1 = 1.f / (1.f + e2);
            const float w2 = e2 / (1.f + e2);
            out[2 * t]     = (float)i1;                    // top_idx as float
            out[2 * t + 1] = (float)i2;
            out[2 * T_TOKENS + 2 * t]     = w1;            // top_weights
            out[2 * T_TOKENS + 2 * t + 1] = w2;
        }
    }
    atomicAdd(&imp[lane], imp_acc);
    atomicAdd(&cnt[lane], cnt_acc);
}

// ---------------------------------------------------------------------------
// Kernel 3: aux_loss = E * sum_e (imp[e]/T) * (cnt[e]/T)
// ---------------------------------------------------------------------------
__global__ void aux_kernel(const float* __restrict__ imp,
                           const float* __restrict__ cnt,
                           float* __restrict__ out_aux)
{
    const int lane = threadIdx.x;
    float v = imp[lane] * cnt[lane];
#pragma unroll
    for (int off = 32; off; off >>= 1) v += __shfl_xor(v, off, 64);
    if (lane == 0)
        out_aux[0] = (float)E_EXP * v / ((float)T_TOKENS * (float)T_TOKENS);
}

extern "C" void kernel_launch(void* const* d_in, const int* in_sizes, int n_in,
                              void* d_out, int out_size, void* d_ws, size_t ws_size,
                              hipStream_t stream)
{
    (void)in_sizes; (void)n_in; (void)out_size; (void)ws_size;
    const float* x      = (const float*)d_in[0];
    const float* rc     = (const float*)d_in[1];
    const float* gate_w = (const float*)d_in[2];
    const float* ctx_w  = (const float*)d_in[3];
    float* out = (float*)d_out;

    float* ctx = (float*)d_ws;        // 8192 floats
    float* imp = ctx + 8192;          // 64 floats
    float* cnt = imp + 64;            // 64 floats

    hipMemsetAsync(imp, 0, 128 * sizeof(float), stream);
    ctx_kernel<<<2048, 256, 0, stream>>>(rc, ctx_w, ctx);
    router_kernel<<<256, 256, 0, stream>>>(x, gate_w, ctx, out, imp, cnt);
    aux_kernel<<<1, 64, 0, stream>>>(imp, cnt, out + 2 * 2 * T_TOKENS);
}